// Round 1
// baseline (271.916 us; speedup 1.0000x reference)
//
#include <hip/hip_runtime.h>
#include <math.h>

#define Hh 16
#define Ll 2048
#define Dd 64
#define MB 32      // L / 64 blocks
#define TK 6
#define PAD 68     // LDS row pad (floats): keeps float4 alignment

// ---------------- K1: block means for q and k ----------------
__global__ void k_blockmean(const float* __restrict__ q, const float* __restrict__ k,
                            float* __restrict__ qb, float* __restrict__ kb) {
  int bid = blockIdx.x;                     // 0..1023: first 512 -> q, next 512 -> k
  const float* src = (bid < Hh * MB) ? q : k;
  float* dst = (bid < Hh * MB) ? qb : kb;
  int hm = bid & (Hh * MB - 1);
  int d = threadIdx.x;                      // 0..63
  const float* base = src + (size_t)hm * (64 * Dd);  // (h*L + m*64)*D == hm*64*D
  float s = 0.f;
#pragma unroll 8
  for (int r = 0; r < 64; ++r) s += base[r * Dd + d];
  dst[hm * Dd + d] = s * (1.0f / 64.0f);
}

// ---------------- K2: block scores + top-6 ----------------
__global__ void k_topk(const float* __restrict__ qb, const float* __restrict__ kb,
                       int* __restrict__ lut) {
  int hm = blockIdx.x;                      // 0..511
  int h = hm / MB;
  __shared__ float sc[MB];
  int n = threadIdx.x;                      // 64 threads, first 32 compute
  if (n < MB) {
    const float* qv = qb + hm * Dd;
    const float* kv = kb + (h * MB + n) * Dd;
    float s = 0.f;
#pragma unroll 8
    for (int d = 0; d < Dd; ++d) s += qv[d] * kv[d];
    sc[n] = s;
  }
  __syncthreads();
  if (threadIdx.x == 0) {
    for (int t = 0; t < TK; ++t) {
      int best = 0; float bv = sc[0];
      for (int n2 = 1; n2 < MB; ++n2) {
        if (sc[n2] > bv) { bv = sc[n2]; best = n2; }
      }
      lut[hm * TK + t] = best;
      sc[best] = -INFINITY;
    }
  }
}

// ---------------- K3: block-sparse flash attention ----------------
__global__ __launch_bounds__(256, 2)
void k_sparse_attn(const float* __restrict__ q, const float* __restrict__ k,
                   const float* __restrict__ v, const int* __restrict__ lut,
                   float* __restrict__ out) {
  __shared__ float q_s[64][PAD];
  __shared__ float k_s[64][PAD];
  __shared__ float v_s[64][PAD];
  __shared__ float p_s[64][PAD];
  __shared__ float row_m[64], row_l[64], row_resc[64];

  int hm = blockIdx.x;                      // 0..511
  int h = hm >> 5, m = hm & 31;
  int t = threadIdx.x;
  int tr = t >> 4;                          // row group: rows tr*4..+3
  int tc = t & 15;                          // col group: cols tc*4..+3
  const float* qbase = q + ((size_t)h * Ll + m * 64) * Dd;

  {
    int r = t >> 4, c4 = t & 15;
#pragma unroll
    for (int ch = 0; ch < 4; ++ch) {
      *reinterpret_cast<float4*>(&q_s[r + ch * 16][c4 * 4]) =
          *reinterpret_cast<const float4*>(qbase + (r + ch * 16) * Dd + c4 * 4);
    }
  }
  if (t < 64) { row_m[t] = -INFINITY; row_l[t] = 0.f; }
  float acc[4][4] = {};
  __syncthreads();

  for (int kbi = 0; kbi < TK; ++kbi) {
    int nb = lut[hm * TK + kbi];
    const float* kbase = k + ((size_t)h * Ll + nb * 64) * Dd;
    const float* vbase = v + ((size_t)h * Ll + nb * 64) * Dd;
    {
      int r = t >> 4, c4 = t & 15;
#pragma unroll
      for (int ch = 0; ch < 4; ++ch) {
        *reinterpret_cast<float4*>(&k_s[r + ch * 16][c4 * 4]) =
            *reinterpret_cast<const float4*>(kbase + (r + ch * 16) * Dd + c4 * 4);
        *reinterpret_cast<float4*>(&v_s[r + ch * 16][c4 * 4]) =
            *reinterpret_cast<const float4*>(vbase + (r + ch * 16) * Dd + c4 * 4);
      }
    }
    __syncthreads();

    // S = Q @ K^T * scale   (4x4 per thread)
    float sacc[4][4] = {};
#pragma unroll
    for (int d4 = 0; d4 < 16; ++d4) {
      float4 qv[4], kv4[4];
#pragma unroll
      for (int i = 0; i < 4; ++i) qv[i] = *reinterpret_cast<const float4*>(&q_s[tr * 4 + i][d4 * 4]);
#pragma unroll
      for (int j = 0; j < 4; ++j) kv4[j] = *reinterpret_cast<const float4*>(&k_s[tc * 4 + j][d4 * 4]);
#pragma unroll
      for (int i = 0; i < 4; ++i)
#pragma unroll
        for (int j = 0; j < 4; ++j)
          sacc[i][j] += qv[i].x * kv4[j].x + qv[i].y * kv4[j].y +
                        qv[i].z * kv4[j].z + qv[i].w * kv4[j].w;
    }
#pragma unroll
    for (int i = 0; i < 4; ++i) {
      float4 sv = make_float4(sacc[i][0] * 0.125f, sacc[i][1] * 0.125f,
                              sacc[i][2] * 0.125f, sacc[i][3] * 0.125f);
      *reinterpret_cast<float4*>(&p_s[tr * 4 + i][tc * 4]) = sv;
    }
    __syncthreads();

    // online softmax update (wave 0, one lane per row)
    if (t < 64) {
      float mold = row_m[t];
      float bm = mold;
#pragma unroll
      for (int kk4 = 0; kk4 < 16; ++kk4) {
        float4 s4 = *reinterpret_cast<const float4*>(&p_s[t][kk4 * 4]);
        bm = fmaxf(bm, fmaxf(fmaxf(s4.x, s4.y), fmaxf(s4.z, s4.w)));
      }
      float resc = __expf(mold - bm);       // first block: exp(-inf)=0
      float sum = 0.f;
#pragma unroll
      for (int kk4 = 0; kk4 < 16; ++kk4) {
        float4 s4 = *reinterpret_cast<const float4*>(&p_s[t][kk4 * 4]);
        s4.x = __expf(s4.x - bm); s4.y = __expf(s4.y - bm);
        s4.z = __expf(s4.z - bm); s4.w = __expf(s4.w - bm);
        sum += s4.x + s4.y + s4.z + s4.w;
        *reinterpret_cast<float4*>(&p_s[t][kk4 * 4]) = s4;
      }
      row_l[t] = row_l[t] * resc + sum;
      row_m[t] = bm;
      row_resc[t] = resc;
    }
    __syncthreads();

    // O = O*resc + P @ V
    float rs[4];
#pragma unroll
    for (int i = 0; i < 4; ++i) rs[i] = row_resc[tr * 4 + i];
#pragma unroll
    for (int i = 0; i < 4; ++i)
#pragma unroll
      for (int j = 0; j < 4; ++j) acc[i][j] *= rs[i];
#pragma unroll
    for (int kk4 = 0; kk4 < 16; ++kk4) {
      float4 pv[4], vv[4];
#pragma unroll
      for (int i = 0; i < 4; ++i) pv[i] = *reinterpret_cast<const float4*>(&p_s[tr * 4 + i][kk4 * 4]);
#pragma unroll
      for (int kl = 0; kl < 4; ++kl) vv[kl] = *reinterpret_cast<const float4*>(&v_s[kk4 * 4 + kl][tc * 4]);
#pragma unroll
      for (int i = 0; i < 4; ++i) {
        const float* pf = reinterpret_cast<const float*>(&pv[i]);
#pragma unroll
        for (int kl = 0; kl < 4; ++kl) {
          const float* vf = reinterpret_cast<const float*>(&vv[kl]);
          float pval = pf[kl];
          acc[i][0] += pval * vf[0];
          acc[i][1] += pval * vf[1];
          acc[i][2] += pval * vf[2];
          acc[i][3] += pval * vf[3];
        }
      }
    }
    __syncthreads();
  }

  // normalize + store
#pragma unroll
  for (int i = 0; i < 4; ++i) {
    int r = tr * 4 + i;
    float inv = 1.0f / row_l[r];
    float4 o = make_float4(acc[i][0] * inv, acc[i][1] * inv,
                           acc[i][2] * inv, acc[i][3] * inv);
    *reinterpret_cast<float4*>(out + ((size_t)h * Ll + m * 64 + r) * Dd + tc * 4) = o;
  }
}

// ---------------- K4: kv_sum and k_sum accumulation ----------------
__global__ __launch_bounds__(256)
void k_linacc(const float* __restrict__ k, const float* __restrict__ v,
              float* __restrict__ kv, float* __restrict__ ksum) {
  int h = blockIdx.x >> 3;
  int c = blockIdx.x & 7;                   // 8 chunks of 256 rows
  int t = threadIdx.x;
  int w = t >> 6, ln = t & 63;
  __shared__ float kf_s[64][PAD];
  __shared__ float v_s[64][PAD];
  __shared__ float ks_part[4][64];
  float kvacc[4][4] = {};
  float kspart = 0.f;
  int da0 = (t >> 4) * 4;
  int e0 = (t & 15) * 4;
  const size_t hbase = (size_t)h * Ll * Dd;

  for (int tile = 0; tile < 4; ++tile) {
    int row0 = c * 256 + tile * 64;
    for (int i = 0; i < 16; ++i) {
      int rl = w * 16 + i;
      int row = row0 + rl;
      float val = k[hbase + (size_t)row * Dd + ln];
      float mx = val;
#pragma unroll
      for (int off = 32; off > 0; off >>= 1) mx = fmaxf(mx, __shfl_xor(mx, off));
      float e = __expf(val - mx);
      float sm = e;
#pragma unroll
      for (int off = 32; off > 0; off >>= 1) sm += __shfl_xor(sm, off);
      float kf = e / sm;
      kf_s[rl][ln] = kf;
      kspart += kf;
      v_s[rl][ln] = v[hbase + (size_t)row * Dd + ln];
    }
    __syncthreads();
    for (int r = 0; r < 64; ++r) {
      float4 kf4 = *reinterpret_cast<const float4*>(&kf_s[r][da0]);
      float4 vv4 = *reinterpret_cast<const float4*>(&v_s[r][e0]);
      const float* kfp = reinterpret_cast<const float*>(&kf4);
      const float* vvp = reinterpret_cast<const float*>(&vv4);
#pragma unroll
      for (int i = 0; i < 4; ++i)
#pragma unroll
        for (int j = 0; j < 4; ++j) kvacc[i][j] += kfp[i] * vvp[j];
    }
    __syncthreads();
  }
#pragma unroll
  for (int i = 0; i < 4; ++i)
#pragma unroll
    for (int j = 0; j < 4; ++j)
      atomicAdd(&kv[h * 4096 + (da0 + i) * 64 + e0 + j], kvacc[i][j]);
  ks_part[w][ln] = kspart;
  __syncthreads();
  if (t < 64) {
    float s = ks_part[0][t] + ks_part[1][t] + ks_part[2][t] + ks_part[3][t];
    atomicAdd(&ksum[h * Dd + t], s);
  }
}

// ---------------- K5: fold projection: kvW[a][e] = sum_b kv[a][b]*W[e][b] ----------------
__global__ __launch_bounds__(256)
void k_fold(const float* __restrict__ kv, const float* __restrict__ W,
            float* __restrict__ kvW) {
  int h = blockIdx.x;
  int t = threadIdx.x;
  __shared__ float kv_s[64][PAD];
  __shared__ float w_s[64][PAD];
  {
    int r = t >> 4, c4 = t & 15;
#pragma unroll
    for (int ch = 0; ch < 4; ++ch) {
      *reinterpret_cast<float4*>(&kv_s[r + ch * 16][c4 * 4]) =
          *reinterpret_cast<const float4*>(kv + h * 4096 + (r + ch * 16) * 64 + c4 * 4);
      *reinterpret_cast<float4*>(&w_s[r + ch * 16][c4 * 4]) =
          *reinterpret_cast<const float4*>(W + (r + ch * 16) * 64 + c4 * 4);
    }
  }
  __syncthreads();
  int a0 = (t >> 4) * 4, e0 = (t & 15) * 4;
  float acc[4][4] = {};
#pragma unroll
  for (int b4 = 0; b4 < 16; ++b4) {
    float4 kv4[4], w4[4];
#pragma unroll
    for (int i = 0; i < 4; ++i) kv4[i] = *reinterpret_cast<const float4*>(&kv_s[a0 + i][b4 * 4]);
#pragma unroll
    for (int j = 0; j < 4; ++j) w4[j] = *reinterpret_cast<const float4*>(&w_s[e0 + j][b4 * 4]);
#pragma unroll
    for (int i = 0; i < 4; ++i)
#pragma unroll
      for (int j = 0; j < 4; ++j)
        acc[i][j] += kv4[i].x * w4[j].x + kv4[i].y * w4[j].y +
                     kv4[i].z * w4[j].z + kv4[i].w * w4[j].w;
  }
#pragma unroll
  for (int i = 0; i < 4; ++i) {
    float4 o = make_float4(acc[i][0], acc[i][1], acc[i][2], acc[i][3]);
    *reinterpret_cast<float4*>(kvW + h * 4096 + (a0 + i) * 64 + e0) = o;
  }
}

// ---------------- K6: o_l = (qf @ kvW)/den + b, added to out ----------------
__global__ __launch_bounds__(256)
void k_linout(const float* __restrict__ q, const float* __restrict__ kvW,
              const float* __restrict__ ksum, const float* __restrict__ bproj,
              float* __restrict__ out) {
  int h = blockIdx.x >> 4;
  int c = blockIdx.x & 15;                  // 16 chunks of 128 rows
  int t = threadIdx.x;
  int w = t >> 6, ln = t & 63;
  __shared__ float kvW_s[64][PAD];          // transposed: [e][a]
  __shared__ float ks_s[64];
  __shared__ float b_s[64];
  __shared__ float qf_s[4][PAD];
#pragma unroll
  for (int ch = 0; ch < 16; ++ch) {
    int idx = ch * 256 + t;
    int a = idx >> 6, e = idx & 63;
    kvW_s[e][a] = kvW[h * 4096 + idx];
  }
  if (t < 64) { ks_s[t] = ksum[h * Dd + t]; b_s[t] = bproj[t]; }
  __syncthreads();
  const size_t hbase = (size_t)h * Ll * Dd;
  for (int i = 0; i < 32; ++i) {
    int row = c * 128 + i * 4 + w;
    float val = q[hbase + (size_t)row * Dd + ln];
    float mx = val;
#pragma unroll
    for (int off = 32; off > 0; off >>= 1) mx = fmaxf(mx, __shfl_xor(mx, off));
    float e = __expf(val - mx);
    float sm = e;
#pragma unroll
    for (int off = 32; off > 0; off >>= 1) sm += __shfl_xor(sm, off);
    float qf = e / sm;
    float dp = qf * ks_s[ln];
#pragma unroll
    for (int off = 32; off > 0; off >>= 1) dp += __shfl_xor(dp, off);
    float den = dp + 1e-5f;
    qf_s[w][ln] = qf;
    __syncthreads();
    float acc = 0.f;
#pragma unroll
    for (int a4 = 0; a4 < 16; ++a4) {
      float4 q4 = *reinterpret_cast<const float4*>(&qf_s[w][a4 * 4]);
      float4 kw4 = *reinterpret_cast<const float4*>(&kvW_s[ln][a4 * 4]);
      acc += q4.x * kw4.x + q4.y * kw4.y + q4.z * kw4.z + q4.w * kw4.w;
    }
    out[hbase + (size_t)row * Dd + ln] += acc / den + b_s[ln];
    __syncthreads();
  }
}

extern "C" void kernel_launch(void* const* d_in, const int* in_sizes, int n_in,
                              void* d_out, int out_size, void* d_ws, size_t ws_size,
                              hipStream_t stream) {
  const float* q = (const float*)d_in[0];
  const float* k = (const float*)d_in[1];
  const float* v = (const float*)d_in[2];
  const float* W = (const float*)d_in[3];
  const float* b = (const float*)d_in[4];
  float* out = (float*)d_out;

  // workspace layout (floats)
  float* ws = (float*)d_ws;
  float* qb   = ws;                          // 16*32*64   = 32768
  float* kb   = ws + 32768;                  // 32768
  float* kv   = ws + 65536;                  // 16*64*64   = 65536
  float* ksum = ws + 131072;                 // 16*64      = 1024
  float* kvW  = ws + 132096;                 // 65536
  int*   lut  = (int*)(ws + 197632);         // 16*32*6    = 3072 ints

  hipMemsetAsync(kv, 0, (65536 + 1024) * sizeof(float), stream);

  k_blockmean<<<1024, 64, 0, stream>>>(q, k, qb, kb);
  k_topk<<<512, 64, 0, stream>>>(qb, kb, lut);
  k_sparse_attn<<<512, 256, 0, stream>>>(q, k, v, lut, out);
  k_linacc<<<128, 256, 0, stream>>>(k, v, kv, ksum);
  k_fold<<<16, 256, 0, stream>>>(kv, W, kvW);
  k_linout<<<256, 256, 0, stream>>>(q, kvW, ksum, b, out);
}

// Round 2
// 115.779 us; speedup vs baseline: 2.3486x; 2.3486x over previous
//
#include <hip/hip_runtime.h>
#include <math.h>

#define Hh 16
#define Ll 2048
#define Dd 64
#define MB 32      // L / 64 blocks
#define TK 6
#define PAD 68

typedef __attribute__((ext_vector_type(8))) short s16x8;
typedef __attribute__((ext_vector_type(4))) float f32x4;

static __device__ __forceinline__ unsigned short f2bf(float x) {
  unsigned int u = __float_as_uint(x);
  return (unsigned short)((u + 0x7fffu + ((u >> 16) & 1u)) >> 16);
}
// byte offset into a [64][*] bf16 tile with 128B rows, XOR-swizzled (T2)
static __device__ __forceinline__ int swz(int row, int bcol) {
  return row * 128 + (bcol ^ ((row & 7) << 4));
}

// ---------------- K1: block means for q and k ----------------
__global__ void k_blockmean(const float* __restrict__ q, const float* __restrict__ k,
                            float* __restrict__ qb, float* __restrict__ kb) {
  int bid = blockIdx.x;
  const float* src = (bid < Hh * MB) ? q : k;
  float* dst = (bid < Hh * MB) ? qb : kb;
  int hm = bid & (Hh * MB - 1);
  int d = threadIdx.x;
  const float* base = src + (size_t)hm * (64 * Dd);
  float s = 0.f;
#pragma unroll 8
  for (int r = 0; r < 64; ++r) s += base[r * Dd + d];
  dst[hm * Dd + d] = s * (1.0f / 64.0f);
}

// ---------------- K2: block scores + top-6 ----------------
__global__ void k_topk(const float* __restrict__ qb, const float* __restrict__ kb,
                       int* __restrict__ lut) {
  int hm = blockIdx.x;
  int h = hm / MB;
  __shared__ float sc[MB];
  int n = threadIdx.x;
  if (n < MB) {
    const float* qv = qb + hm * Dd;
    const float* kv = kb + (h * MB + n) * Dd;
    float s = 0.f;
#pragma unroll 8
    for (int d = 0; d < Dd; ++d) s += qv[d] * kv[d];
    sc[n] = s;
  }
  __syncthreads();
  if (threadIdx.x == 0) {
    for (int t = 0; t < TK; ++t) {
      int best = 0; float bv = sc[0];
      for (int n2 = 1; n2 < MB; ++n2) {
        if (sc[n2] > bv) { bv = sc[n2]; best = n2; }
      }
      lut[hm * TK + t] = best;
      sc[best] = -INFINITY;
    }
  }
}

// ---------------- K3: block-sparse flash attention, bf16 MFMA ----------------
__global__ __launch_bounds__(256, 2)
void k_sparse_attn(const float* __restrict__ q, const float* __restrict__ k,
                   const float* __restrict__ v, const int* __restrict__ lut,
                   float* __restrict__ out) {
  __shared__ unsigned short k_s[2][4096];  // [key][d] bf16, swizzled
  __shared__ unsigned short v_s[2][4096];  // [d][key] bf16 (V^T), swizzled
  __shared__ unsigned short p_s[4][1024];  // per-wave [16 q][64 key] bf16, swizzled

  int bid = blockIdx.x;
  int hm = (bid & 7) * 64 + (bid >> 3);    // XCD-bijective: head pair per XCD
  int h = hm >> 5, m = hm & 31;
  int t = threadIdx.x, w = t >> 6, l = t & 63;
  int g = l >> 4, c16 = l & 15;

  const float* qg = q + ((size_t)h * Ll + m * 64) * Dd;

  // preload Q A-frags (scaled by 1/sqrt(D)=0.125), rows w*16+c16
  s16x8 aq[2];
#pragma unroll
  for (int kc = 0; kc < 2; ++kc) {
    const float* p0 = qg + (w * 16 + c16) * Dd + kc * 32 + g * 8;
    float4 x = *(const float4*)p0;
    float4 y = *(const float4*)(p0 + 4);
    s16x8 a;
    a[0] = f2bf(x.x * 0.125f); a[1] = f2bf(x.y * 0.125f);
    a[2] = f2bf(x.z * 0.125f); a[3] = f2bf(x.w * 0.125f);
    a[4] = f2bf(y.x * 0.125f); a[5] = f2bf(y.y * 0.125f);
    a[6] = f2bf(y.z * 0.125f); a[7] = f2bf(y.w * 0.125f);
    aq[kc] = a;
  }

  auto stage = [&](int buf, int nb) {
    const float* kb = k + ((size_t)h * Ll + nb * 64) * Dd;
    const float* vb = v + ((size_t)h * Ll + nb * 64) * Dd;
    // K: 2 x 16B bf16 chunks per thread, row-major swizzled
#pragma unroll
    for (int cc = 0; cc < 2; ++cc) {
      int c = t + cc * 256;
      int row = c >> 3, col16 = c & 7;
      const float* p0 = kb + row * Dd + col16 * 8;
      float4 x = *(const float4*)p0, y = *(const float4*)(p0 + 4);
      s16x8 a;
      a[0] = f2bf(x.x); a[1] = f2bf(x.y); a[2] = f2bf(x.z); a[3] = f2bf(x.w);
      a[4] = f2bf(y.x); a[5] = f2bf(y.y); a[6] = f2bf(y.z); a[7] = f2bf(y.w);
      *(s16x8*)&k_s[buf][swz(row, col16 * 16) >> 1] = a;
    }
    // V transposed: wave w covers keys w*16..+15
    int key = w * 16 + (l >> 2);
    int dc = (l & 3) * 4;
#pragma unroll
    for (int p = 0; p < 4; ++p) {
      int d0 = p * 16 + dc;
      float4 xv = *(const float4*)(vb + key * Dd + d0);
      v_s[buf][swz(d0 + 0, key * 2) >> 1] = f2bf(xv.x);
      v_s[buf][swz(d0 + 1, key * 2) >> 1] = f2bf(xv.y);
      v_s[buf][swz(d0 + 2, key * 2) >> 1] = f2bf(xv.z);
      v_s[buf][swz(d0 + 3, key * 2) >> 1] = f2bf(xv.w);
    }
  };

  float mrow[4] = {-INFINITY, -INFINITY, -INFINITY, -INFINITY};
  float lrow[4] = {0.f, 0.f, 0.f, 0.f};
  f32x4 o[4] = {};

  stage(0, lut[hm * TK]);
  __syncthreads();

  for (int kbi = 0; kbi < TK; ++kbi) {
    int buf = kbi & 1;
    if (kbi + 1 < TK) stage(buf ^ 1, lut[hm * TK + kbi + 1]);

    // S = Q K^T : 4 key-tiles x 2 K-chunks
    f32x4 s[4];
#pragma unroll
    for (int nt = 0; nt < 4; ++nt) {
      s16x8 b0 = *(const s16x8*)&k_s[buf][swz(nt * 16 + c16, g * 16) >> 1];
      s16x8 b1 = *(const s16x8*)&k_s[buf][swz(nt * 16 + c16, 64 + g * 16) >> 1];
      f32x4 z = {0.f, 0.f, 0.f, 0.f};
      z = __builtin_amdgcn_mfma_f32_16x16x32_bf16(aq[0], b0, z, 0, 0, 0);
      s[nt] = __builtin_amdgcn_mfma_f32_16x16x32_bf16(aq[1], b1, z, 0, 0, 0);
    }

    // in-register online softmax (row = g*4+r, cols spread over 16 lanes x 4 nt)
#pragma unroll
    for (int r = 0; r < 4; ++r) {
      float mx = fmaxf(fmaxf(s[0][r], s[1][r]), fmaxf(s[2][r], s[3][r]));
#pragma unroll
      for (int off = 8; off; off >>= 1) mx = fmaxf(mx, __shfl_xor(mx, off));
      float nm = fmaxf(mrow[r], mx);
      float rs = __expf(mrow[r] - nm);
      float sum = 0.f;
      int qrow = g * 4 + r;
#pragma unroll
      for (int nt = 0; nt < 4; ++nt) {
        float pv = __expf(s[nt][r] - nm);
        sum += pv;
        p_s[w][swz(qrow, (nt * 16 + c16) * 2) >> 1] = f2bf(pv);
      }
#pragma unroll
      for (int off = 8; off; off >>= 1) sum += __shfl_xor(sum, off);
      lrow[r] = lrow[r] * rs + sum;
      mrow[r] = nm;
      o[0][r] *= rs; o[1][r] *= rs; o[2][r] *= rs; o[3][r] *= rs;
    }

    // wave-private p_s RAW: drain LDS writes before fragment reads
    asm volatile("s_waitcnt lgkmcnt(0)" ::: "memory");

    // O += P V : A = P from p_s, B = V from v_s (V^T layout)
    s16x8 ap0 = *(const s16x8*)&p_s[w][swz(c16, g * 16) >> 1];
    s16x8 ap1 = *(const s16x8*)&p_s[w][swz(c16, 64 + g * 16) >> 1];
#pragma unroll
    for (int nt = 0; nt < 4; ++nt) {
      s16x8 b0 = *(const s16x8*)&v_s[buf][swz(nt * 16 + c16, g * 16) >> 1];
      s16x8 b1 = *(const s16x8*)&v_s[buf][swz(nt * 16 + c16, 64 + g * 16) >> 1];
      o[nt] = __builtin_amdgcn_mfma_f32_16x16x32_bf16(ap0, b0, o[nt], 0, 0, 0);
      o[nt] = __builtin_amdgcn_mfma_f32_16x16x32_bf16(ap1, b1, o[nt], 0, 0, 0);
    }
    __syncthreads();
  }

  // epilogue: normalize + store (C layout: row=g*4+r, col=nt*16+c16)
  float* ob = out + ((size_t)h * Ll + m * 64 + w * 16) * Dd;
#pragma unroll
  for (int r = 0; r < 4; ++r) {
    float inv = 1.0f / lrow[r];
    int qrow = g * 4 + r;
#pragma unroll
    for (int nt = 0; nt < 4; ++nt)
      ob[qrow * Dd + nt * 16 + c16] = o[nt][r] * inv;
  }
}

// ---------------- K4: kv_sum and k_sum accumulation (512 wgs) ----------------
__global__ __launch_bounds__(256)
void k_linacc(const float* __restrict__ k, const float* __restrict__ v,
              float* __restrict__ kv, float* __restrict__ ksum) {
  int h = blockIdx.x >> 5;
  int c = blockIdx.x & 31;                  // 32 chunks of 64 rows
  int t = threadIdx.x;
  int w = t >> 6, ln = t & 63;
  __shared__ float kf_s[64][PAD];
  __shared__ float v_sh[64][PAD];
  __shared__ float ks_part[4][64];
  float kvacc[4][4] = {};
  float kspart = 0.f;
  int da0 = (t >> 4) * 4;
  int e0 = (t & 15) * 4;
  const size_t hbase = (size_t)h * Ll * Dd;
  int row0 = c * 64;

  for (int i = 0; i < 16; ++i) {
    int rl = w * 16 + i;
    int row = row0 + rl;
    float val = k[hbase + (size_t)row * Dd + ln];
    float mx = val;
#pragma unroll
    for (int off = 32; off > 0; off >>= 1) mx = fmaxf(mx, __shfl_xor(mx, off));
    float e = __expf(val - mx);
    float sm = e;
#pragma unroll
    for (int off = 32; off > 0; off >>= 1) sm += __shfl_xor(sm, off);
    float kf = e / sm;
    kf_s[rl][ln] = kf;
    kspart += kf;
    v_sh[rl][ln] = v[hbase + (size_t)row * Dd + ln];
  }
  __syncthreads();
  for (int r = 0; r < 64; ++r) {
    float4 kf4 = *reinterpret_cast<const float4*>(&kf_s[r][da0]);
    float4 vv4 = *reinterpret_cast<const float4*>(&v_sh[r][e0]);
    const float* kfp = reinterpret_cast<const float*>(&kf4);
    const float* vvp = reinterpret_cast<const float*>(&vv4);
#pragma unroll
    for (int i = 0; i < 4; ++i)
#pragma unroll
      for (int j = 0; j < 4; ++j) kvacc[i][j] += kfp[i] * vvp[j];
  }
#pragma unroll
  for (int i = 0; i < 4; ++i)
#pragma unroll
    for (int j = 0; j < 4; ++j)
      atomicAdd(&kv[h * 4096 + (da0 + i) * 64 + e0 + j], kvacc[i][j]);
  ks_part[w][ln] = kspart;
  __syncthreads();
  if (t < 64) {
    float s = ks_part[0][t] + ks_part[1][t] + ks_part[2][t] + ks_part[3][t];
    atomicAdd(&ksum[h * Dd + t], s);
  }
}

// ---------------- K5: fold projection ----------------
__global__ __launch_bounds__(256)
void k_fold(const float* __restrict__ kv, const float* __restrict__ W,
            float* __restrict__ kvW) {
  int h = blockIdx.x;
  int t = threadIdx.x;
  __shared__ float kv_s[64][PAD];
  __shared__ float w_s[64][PAD];
  {
    int r = t >> 4, c4 = t & 15;
#pragma unroll
    for (int ch = 0; ch < 4; ++ch) {
      *reinterpret_cast<float4*>(&kv_s[r + ch * 16][c4 * 4]) =
          *reinterpret_cast<const float4*>(kv + h * 4096 + (r + ch * 16) * 64 + c4 * 4);
      *reinterpret_cast<float4*>(&w_s[r + ch * 16][c4 * 4]) =
          *reinterpret_cast<const float4*>(W + (r + ch * 16) * 64 + c4 * 4);
    }
  }
  __syncthreads();
  int a0 = (t >> 4) * 4, e0 = (t & 15) * 4;
  float acc[4][4] = {};
#pragma unroll
  for (int b4 = 0; b4 < 16; ++b4) {
    float4 kv4[4], w4[4];
#pragma unroll
    for (int i = 0; i < 4; ++i) kv4[i] = *reinterpret_cast<const float4*>(&kv_s[a0 + i][b4 * 4]);
#pragma unroll
    for (int j = 0; j < 4; ++j) w4[j] = *reinterpret_cast<const float4*>(&w_s[e0 + j][b4 * 4]);
#pragma unroll
    for (int i = 0; i < 4; ++i)
#pragma unroll
      for (int j = 0; j < 4; ++j)
        acc[i][j] += kv4[i].x * w4[j].x + kv4[i].y * w4[j].y +
                     kv4[i].z * w4[j].z + kv4[i].w * w4[j].w;
  }
#pragma unroll
  for (int i = 0; i < 4; ++i) {
    float4 ov = make_float4(acc[i][0], acc[i][1], acc[i][2], acc[i][3]);
    *reinterpret_cast<float4*>(kvW + h * 4096 + (a0 + i) * 64 + e0) = ov;
  }
}

// ---------------- K6: o_l added to out (512 wgs, no in-loop barriers) ----------------
__global__ __launch_bounds__(256)
void k_linout(const float* __restrict__ q, const float* __restrict__ kvW,
              const float* __restrict__ ksum, const float* __restrict__ bproj,
              float* __restrict__ out) {
  int h = blockIdx.x >> 5;
  int c = blockIdx.x & 31;                  // 32 chunks of 64 rows
  int t = threadIdx.x;
  int w = t >> 6, ln = t & 63;
  __shared__ float kvW_s[64][PAD];          // transposed: [e][a]
  __shared__ float ks_s[64];
  __shared__ float b_s[64];
  __shared__ float qf_s[4][PAD];            // wave-private rows
#pragma unroll
  for (int ch = 0; ch < 16; ++ch) {
    int idx = ch * 256 + t;
    int a = idx >> 6, e = idx & 63;
    kvW_s[e][a] = kvW[h * 4096 + idx];
  }
  if (t < 64) { ks_s[t] = ksum[h * Dd + t]; b_s[t] = bproj[t]; }
  __syncthreads();
  const size_t hbase = (size_t)h * Ll * Dd;
  for (int i = 0; i < 16; ++i) {
    int row = c * 64 + i * 4 + w;
    float val = q[hbase + (size_t)row * Dd + ln];
    float mx = val;
#pragma unroll
    for (int off = 32; off > 0; off >>= 1) mx = fmaxf(mx, __shfl_xor(mx, off));
    float e = __expf(val - mx);
    float sm = e;
#pragma unroll
    for (int off = 32; off > 0; off >>= 1) sm += __shfl_xor(sm, off);
    float qf = e / sm;
    float dp = qf * ks_s[ln];
#pragma unroll
    for (int off = 32; off > 0; off >>= 1) dp += __shfl_xor(dp, off);
    float den = dp + 1e-5f;
    qf_s[w][ln] = qf;                       // wave-private: no barrier needed
    float acc = 0.f;
#pragma unroll
    for (int a4 = 0; a4 < 16; ++a4) {
      float4 q4 = *reinterpret_cast<const float4*>(&qf_s[w][a4 * 4]);
      float4 kw4 = *reinterpret_cast<const float4*>(&kvW_s[ln][a4 * 4]);
      acc += q4.x * kw4.x + q4.y * kw4.y + q4.z * kw4.z + q4.w * kw4.w;
    }
    out[hbase + (size_t)row * Dd + ln] += acc / den + b_s[ln];
  }
}

extern "C" void kernel_launch(void* const* d_in, const int* in_sizes, int n_in,
                              void* d_out, int out_size, void* d_ws, size_t ws_size,
                              hipStream_t stream) {
  const float* q = (const float*)d_in[0];
  const float* k = (const float*)d_in[1];
  const float* v = (const float*)d_in[2];
  const float* W = (const float*)d_in[3];
  const float* b = (const float*)d_in[4];
  float* out = (float*)d_out;

  float* ws = (float*)d_ws;
  float* qb   = ws;                          // 32768
  float* kb   = ws + 32768;                  // 32768
  float* kv   = ws + 65536;                  // 65536
  float* ksum = ws + 131072;                 // 1024
  float* kvW  = ws + 132096;                 // 65536
  int*   lut  = (int*)(ws + 197632);         // 3072 ints

  hipMemsetAsync(kv, 0, (65536 + 1024) * sizeof(float), stream);

  k_blockmean<<<1024, 64, 0, stream>>>(q, k, qb, kb);
  k_topk<<<512, 64, 0, stream>>>(qb, kb, lut);
  k_sparse_attn<<<512, 256, 0, stream>>>(q, k, v, lut, out);
  k_linacc<<<512, 256, 0, stream>>>(k, v, kv, ksum);
  k_fold<<<16, 256, 0, stream>>>(kv, W, kvW);
  k_linout<<<512, 256, 0, stream>>>(q, kvW, ksum, b, out);
}

// Round 3
// 61.670 us; speedup vs baseline: 4.4092x; 1.8774x over previous
//
#include <hip/hip_runtime.h>
#include <math.h>

#define Hh 16
#define Ll 2048
#define Dd 64
#define MB 32      // L / 64 blocks
#define TK 6

typedef __attribute__((ext_vector_type(8))) short s16x8;
typedef __attribute__((ext_vector_type(4))) short s16x4;
typedef __attribute__((ext_vector_type(4))) float f32x4;

static __device__ __forceinline__ unsigned short f2bf(float x) {
  unsigned int u = __float_as_uint(x);
  return (unsigned short)((u + 0x7fffu + ((u >> 16) & 1u)) >> 16);
}
// byte offset into a [64][64] bf16 tile with 128B rows, XOR-swizzled (T2)
static __device__ __forceinline__ int swz(int row, int bcol) {
  return row * 128 + (bcol ^ ((row & 7) << 4));
}

// ---------------- K1: block means for q and k ----------------
__global__ void k_blockmean(const float* __restrict__ q, const float* __restrict__ k,
                            float* __restrict__ qb, float* __restrict__ kb) {
  int bid = blockIdx.x;
  const float* src = (bid < Hh * MB) ? q : k;
  float* dst = (bid < Hh * MB) ? qb : kb;
  int hm = bid & (Hh * MB - 1);
  int d = threadIdx.x;
  const float* base = src + (size_t)hm * (64 * Dd);
  float s = 0.f;
#pragma unroll 8
  for (int r = 0; r < 64; ++r) s += base[r * Dd + d];
  dst[hm * Dd + d] = s * (1.0f / 64.0f);
}

// ---------------- K2: block scores + top-6 ----------------
__global__ void k_topk(const float* __restrict__ qb, const float* __restrict__ kb,
                       int* __restrict__ lut) {
  int hm = blockIdx.x;
  int h = hm / MB;
  __shared__ float sc[MB];
  int n = threadIdx.x;
  if (n < MB) {
    const float* qv = qb + hm * Dd;
    const float* kv = kb + (h * MB + n) * Dd;
    float s = 0.f;
#pragma unroll 8
    for (int d = 0; d < Dd; ++d) s += qv[d] * kv[d];
    sc[n] = s;
  }
  __syncthreads();
  if (threadIdx.x == 0) {
    for (int t = 0; t < TK; ++t) {
      int best = 0; float bv = sc[0];
      for (int n2 = 1; n2 < MB; ++n2) {
        if (sc[n2] > bv) { bv = sc[n2]; best = n2; }
      }
      lut[hm * TK + t] = best;
      sc[best] = -INFINITY;
    }
  }
}

// ---------------- K3: block-sparse flash attention, bf16 MFMA ----------------
__global__ __launch_bounds__(256, 2)
void k_sparse_attn(const float* __restrict__ q, const float* __restrict__ k,
                   const float* __restrict__ v, const int* __restrict__ lut,
                   float* __restrict__ out) {
  __shared__ unsigned short k_s[2][4096];  // [key][d] bf16, swizzled
  __shared__ unsigned short v_s[2][4096];  // [d][key] bf16 (V^T), swizzled
  __shared__ unsigned short p_s[4][1024];  // per-wave [16 q][64 key] bf16, swizzled

  int bid = blockIdx.x;
  int hm = (bid & 7) * 64 + (bid >> 3);    // XCD-bijective swizzle
  int h = hm >> 5, m = hm & 31;
  int t = threadIdx.x, w = t >> 6, l = t & 63;
  int g = l >> 4, c16 = l & 15;

  const float* qg = q + ((size_t)h * Ll + m * 64) * Dd;

  s16x8 aq[2];
#pragma unroll
  for (int kc = 0; kc < 2; ++kc) {
    const float* p0 = qg + (w * 16 + c16) * Dd + kc * 32 + g * 8;
    float4 x = *(const float4*)p0;
    float4 y = *(const float4*)(p0 + 4);
    s16x8 a;
    a[0] = f2bf(x.x * 0.125f); a[1] = f2bf(x.y * 0.125f);
    a[2] = f2bf(x.z * 0.125f); a[3] = f2bf(x.w * 0.125f);
    a[4] = f2bf(y.x * 0.125f); a[5] = f2bf(y.y * 0.125f);
    a[6] = f2bf(y.z * 0.125f); a[7] = f2bf(y.w * 0.125f);
    aq[kc] = a;
  }

  auto stage = [&](int buf, int nb) {
    const float* kb = k + ((size_t)h * Ll + nb * 64) * Dd;
    const float* vb = v + ((size_t)h * Ll + nb * 64) * Dd;
#pragma unroll
    for (int cc = 0; cc < 2; ++cc) {
      int c = t + cc * 256;
      int row = c >> 3, col16 = c & 7;
      const float* p0 = kb + row * Dd + col16 * 8;
      float4 x = *(const float4*)p0, y = *(const float4*)(p0 + 4);
      s16x8 a;
      a[0] = f2bf(x.x); a[1] = f2bf(x.y); a[2] = f2bf(x.z); a[3] = f2bf(x.w);
      a[4] = f2bf(y.x); a[5] = f2bf(y.y); a[6] = f2bf(y.z); a[7] = f2bf(y.w);
      *(s16x8*)&k_s[buf][swz(row, col16 * 16) >> 1] = a;
    }
    int key = w * 16 + (l >> 2);
    int dc = (l & 3) * 4;
#pragma unroll
    for (int p = 0; p < 4; ++p) {
      int d0 = p * 16 + dc;
      float4 xv = *(const float4*)(vb + key * Dd + d0);
      v_s[buf][swz(d0 + 0, key * 2) >> 1] = f2bf(xv.x);
      v_s[buf][swz(d0 + 1, key * 2) >> 1] = f2bf(xv.y);
      v_s[buf][swz(d0 + 2, key * 2) >> 1] = f2bf(xv.z);
      v_s[buf][swz(d0 + 3, key * 2) >> 1] = f2bf(xv.w);
    }
  };

  float mrow[4] = {-INFINITY, -INFINITY, -INFINITY, -INFINITY};
  float lrow[4] = {0.f, 0.f, 0.f, 0.f};
  f32x4 o[4] = {};

  stage(0, lut[hm * TK]);
  __syncthreads();

  for (int kbi = 0; kbi < TK; ++kbi) {
    int buf = kbi & 1;
    if (kbi + 1 < TK) stage(buf ^ 1, lut[hm * TK + kbi + 1]);

    f32x4 s[4];
#pragma unroll
    for (int nt = 0; nt < 4; ++nt) {
      s16x8 b0 = *(const s16x8*)&k_s[buf][swz(nt * 16 + c16, g * 16) >> 1];
      s16x8 b1 = *(const s16x8*)&k_s[buf][swz(nt * 16 + c16, 64 + g * 16) >> 1];
      f32x4 z = {0.f, 0.f, 0.f, 0.f};
      z = __builtin_amdgcn_mfma_f32_16x16x32_bf16(aq[0], b0, z, 0, 0, 0);
      s[nt] = __builtin_amdgcn_mfma_f32_16x16x32_bf16(aq[1], b1, z, 0, 0, 0);
    }

#pragma unroll
    for (int r = 0; r < 4; ++r) {
      float mx = fmaxf(fmaxf(s[0][r], s[1][r]), fmaxf(s[2][r], s[3][r]));
#pragma unroll
      for (int off = 8; off; off >>= 1) mx = fmaxf(mx, __shfl_xor(mx, off));
      float nm = fmaxf(mrow[r], mx);
      float rs = __expf(mrow[r] - nm);
      float sum = 0.f;
      int qrow = g * 4 + r;
#pragma unroll
      for (int nt = 0; nt < 4; ++nt) {
        float pv = __expf(s[nt][r] - nm);
        sum += pv;
        p_s[w][swz(qrow, (nt * 16 + c16) * 2) >> 1] = f2bf(pv);
      }
#pragma unroll
      for (int off = 8; off; off >>= 1) sum += __shfl_xor(sum, off);
      lrow[r] = lrow[r] * rs + sum;
      mrow[r] = nm;
      o[0][r] *= rs; o[1][r] *= rs; o[2][r] *= rs; o[3][r] *= rs;
    }

    asm volatile("s_waitcnt lgkmcnt(0)" ::: "memory");

    s16x8 ap0 = *(const s16x8*)&p_s[w][swz(c16, g * 16) >> 1];
    s16x8 ap1 = *(const s16x8*)&p_s[w][swz(c16, 64 + g * 16) >> 1];
#pragma unroll
    for (int nt = 0; nt < 4; ++nt) {
      s16x8 b0 = *(const s16x8*)&v_s[buf][swz(nt * 16 + c16, g * 16) >> 1];
      s16x8 b1 = *(const s16x8*)&v_s[buf][swz(nt * 16 + c16, 64 + g * 16) >> 1];
      o[nt] = __builtin_amdgcn_mfma_f32_16x16x32_bf16(ap0, b0, o[nt], 0, 0, 0);
      o[nt] = __builtin_amdgcn_mfma_f32_16x16x32_bf16(ap1, b1, o[nt], 0, 0, 0);
    }
    __syncthreads();
  }

  float* ob = out + ((size_t)h * Ll + m * 64 + w * 16) * Dd;
#pragma unroll
  for (int r = 0; r < 4; ++r) {
    float inv = 1.0f / lrow[r];
    int qrow = g * 4 + r;
#pragma unroll
    for (int nt = 0; nt < 4; ++nt)
      ob[qrow * Dd + nt * 16 + c16] = o[nt][r] * inv;
  }
}

// ---------------- K4: kv/ksum partials, no atomics ----------------
__global__ __launch_bounds__(256)
void k_linacc(const float* __restrict__ k, const float* __restrict__ v,
              float* __restrict__ part_kv, float* __restrict__ part_ks) {
  __shared__ float kf_s[64][68];
  __shared__ float v_sh[64][68];
  int h = blockIdx.x >> 4, c = blockIdx.x & 15;   // 16 chunks of 128 rows
  int t = threadIdx.x;
  int rg = t >> 4;
  int c4 = (t & 15) * 4;
  int da0 = (t >> 4) * 4, e0 = (t & 15) * 4;
  float kvacc[4][4] = {};
  float ks4[4] = {0.f, 0.f, 0.f, 0.f};
  const size_t hbase = (size_t)h * Ll * Dd;
  int rbase = c * 128;

  for (int half = 0; half < 2; ++half) {
#pragma unroll
    for (int ch = 0; ch < 4; ++ch) {
      int rl = ch * 16 + rg;
      int row = rbase + half * 64 + rl;
      float4 kq = *(const float4*)(k + hbase + (size_t)row * Dd + c4);
      float4 vv = *(const float4*)(v + hbase + (size_t)row * Dd + c4);
      float mx = fmaxf(fmaxf(kq.x, kq.y), fmaxf(kq.z, kq.w));
#pragma unroll
      for (int off = 8; off; off >>= 1) mx = fmaxf(mx, __shfl_xor(mx, off));
      float ex = __expf(kq.x - mx), ey = __expf(kq.y - mx);
      float ez = __expf(kq.z - mx), ew = __expf(kq.w - mx);
      float sm = ex + ey + ez + ew;
#pragma unroll
      for (int off = 8; off; off >>= 1) sm += __shfl_xor(sm, off);
      float inv = 1.0f / sm;
      *(float4*)&kf_s[rl][c4] = make_float4(ex * inv, ey * inv, ez * inv, ew * inv);
      *(float4*)&v_sh[rl][c4] = vv;
    }
    __syncthreads();
    for (int r = 0; r < 64; ++r) {
      float4 kf = *(const float4*)&kf_s[r][da0];
      float4 vv = *(const float4*)&v_sh[r][e0];
      ks4[0] += kf.x; ks4[1] += kf.y; ks4[2] += kf.z; ks4[3] += kf.w;
      kvacc[0][0] += kf.x * vv.x; kvacc[0][1] += kf.x * vv.y; kvacc[0][2] += kf.x * vv.z; kvacc[0][3] += kf.x * vv.w;
      kvacc[1][0] += kf.y * vv.x; kvacc[1][1] += kf.y * vv.y; kvacc[1][2] += kf.y * vv.z; kvacc[1][3] += kf.y * vv.w;
      kvacc[2][0] += kf.z * vv.x; kvacc[2][1] += kf.z * vv.y; kvacc[2][2] += kf.z * vv.z; kvacc[2][3] += kf.z * vv.w;
      kvacc[3][0] += kf.w * vv.x; kvacc[3][1] += kf.w * vv.y; kvacc[3][2] += kf.w * vv.z; kvacc[3][3] += kf.w * vv.w;
    }
    __syncthreads();
  }
  float* pkv = part_kv + (size_t)blockIdx.x * 4096;
#pragma unroll
  for (int i = 0; i < 4; ++i)
    *(float4*)(pkv + (da0 + i) * 64 + e0) =
        make_float4(kvacc[i][0], kvacc[i][1], kvacc[i][2], kvacc[i][3]);
  if ((t & 15) == 0) {
#pragma unroll
    for (int i = 0; i < 4; ++i) part_ks[blockIdx.x * 64 + da0 + i] = ks4[i];
  }
}

// ---------------- K5: reduce partials + fold W -> kvWt bf16 ----------------
__global__ __launch_bounds__(256)
void k_fold(const float* __restrict__ part_kv, const float* __restrict__ part_ks,
            const float* __restrict__ W, float* __restrict__ ksum,
            unsigned short* __restrict__ kvwt) {
  __shared__ float kvr[16][68];
  __shared__ float w_s[64][65];
  int h = blockIdx.x >> 2, qtr = blockIdx.x & 3;
  int a0 = qtr * 16;
  int t = threadIdx.x;
  {
    int a = t >> 4, b4 = (t & 15) * 4;
    float4 acc = make_float4(0.f, 0.f, 0.f, 0.f);
    for (int cc = 0; cc < 16; ++cc) {
      float4 p = *(const float4*)(part_kv + (size_t)(h * 16 + cc) * 4096 + (a0 + a) * 64 + b4);
      acc.x += p.x; acc.y += p.y; acc.z += p.z; acc.w += p.w;
    }
    *(float4*)&kvr[a][b4] = acc;
    int r = t >> 2, cq = (t & 3) * 16;
#pragma unroll
    for (int j = 0; j < 16; ++j) w_s[r][cq + j] = W[r * 64 + cq + j];
    if (qtr == 0 && t < 64) {
      float s = 0.f;
      for (int cc = 0; cc < 16; ++cc) s += part_ks[(h * 16 + cc) * 64 + t];
      ksum[h * 64 + t] = s;
    }
  }
  __syncthreads();
  int e = t & 63, ag = t >> 6;
  float acc4[4] = {0.f, 0.f, 0.f, 0.f};
  for (int b = 0; b < 64; ++b) {
    float wv = w_s[e][b];
#pragma unroll
    for (int i = 0; i < 4; ++i) acc4[i] += kvr[ag * 4 + i][b] * wv;
  }
#pragma unroll
  for (int i = 0; i < 4; ++i)
    kvwt[h * 4096 + e * 64 + a0 + ag * 4 + i] = f2bf(acc4[i]);
}

// ---------------- K6: o_l via MFMA, added to out ----------------
__global__ __launch_bounds__(256)
void k_linout(const float* __restrict__ q, const unsigned short* __restrict__ kvwt,
              const float* __restrict__ ksum, const float* __restrict__ bproj,
              float* __restrict__ out) {
  __shared__ unsigned short kvwt_s[4096];   // [e][a] bf16 swizzled
  __shared__ unsigned short qf_s[4][1024];  // per-wave [16 q][64 a] bf16 swizzled
  __shared__ float ks_s[64], b_s[64];
  __shared__ float den_s[4][16];
  int h = blockIdx.x >> 5, c = blockIdx.x & 31;
  int t = threadIdx.x, w = t >> 6, l = t & 63;
  int g = l >> 4, c16 = l & 15;
  int c4 = c16 * 4;

#pragma unroll
  for (int cc = 0; cc < 2; ++cc) {
    int idx = t + cc * 256;
    int row = idx >> 3, col8 = idx & 7;
    s16x8 val = *(const s16x8*)(kvwt + h * 4096 + row * 64 + col8 * 8);
    *(s16x8*)&kvwt_s[swz(row, col8 * 16) >> 1] = val;
  }
  if (t < 64) { ks_s[t] = ksum[h * 64 + t]; b_s[t] = bproj[t]; }
  __syncthreads();

  const float* qg = q + ((size_t)h * Ll + c * 64 + w * 16) * Dd;
#pragma unroll
  for (int p = 0; p < 4; ++p) {
    int rl = p * 4 + g;
    float4 qv = *(const float4*)(qg + rl * Dd + c4);
    float mx = fmaxf(fmaxf(qv.x, qv.y), fmaxf(qv.z, qv.w));
#pragma unroll
    for (int off = 8; off; off >>= 1) mx = fmaxf(mx, __shfl_xor(mx, off));
    float ex = __expf(qv.x - mx), ey = __expf(qv.y - mx);
    float ez = __expf(qv.z - mx), ew = __expf(qv.w - mx);
    float sm = ex + ey + ez + ew;
#pragma unroll
    for (int off = 8; off; off >>= 1) sm += __shfl_xor(sm, off);
    float inv = 1.0f / sm;
    float fx = ex * inv, fy = ey * inv, fz = ez * inv, fw = ew * inv;
    float dp = fx * ks_s[c4] + fy * ks_s[c4 + 1] + fz * ks_s[c4 + 2] + fw * ks_s[c4 + 3];
#pragma unroll
    for (int off = 8; off; off >>= 1) dp += __shfl_xor(dp, off);
    if (c16 == 0) den_s[w][rl] = dp + 1e-5f;
    s16x4 pk;
    pk[0] = f2bf(fx); pk[1] = f2bf(fy); pk[2] = f2bf(fz); pk[3] = f2bf(fw);
    *(s16x4*)&qf_s[w][swz(rl, c4 * 2) >> 1] = pk;
  }
  asm volatile("s_waitcnt lgkmcnt(0)" ::: "memory");

  s16x8 ap0 = *(const s16x8*)&qf_s[w][swz(c16, g * 16) >> 1];
  s16x8 ap1 = *(const s16x8*)&qf_s[w][swz(c16, 64 + g * 16) >> 1];
  f32x4 o[4];
#pragma unroll
  for (int nt = 0; nt < 4; ++nt) {
    s16x8 b0 = *(const s16x8*)&kvwt_s[swz(nt * 16 + c16, g * 16) >> 1];
    s16x8 b1 = *(const s16x8*)&kvwt_s[swz(nt * 16 + c16, 64 + g * 16) >> 1];
    f32x4 z = {0.f, 0.f, 0.f, 0.f};
    z = __builtin_amdgcn_mfma_f32_16x16x32_bf16(ap0, b0, z, 0, 0, 0);
    o[nt] = __builtin_amdgcn_mfma_f32_16x16x32_bf16(ap1, b1, z, 0, 0, 0);
  }

  float* ob = out + ((size_t)h * Ll + c * 64 + w * 16) * Dd;
#pragma unroll
  for (int r = 0; r < 4; ++r) {
    int qrow = g * 4 + r;
    float invd = 1.0f / den_s[w][qrow];
#pragma unroll
    for (int nt = 0; nt < 4; ++nt)
      ob[qrow * Dd + nt * 16 + c16] += o[nt][r] * invd + b_s[nt * 16 + c16];
  }
}

extern "C" void kernel_launch(void* const* d_in, const int* in_sizes, int n_in,
                              void* d_out, int out_size, void* d_ws, size_t ws_size,
                              hipStream_t stream) {
  const float* q = (const float*)d_in[0];
  const float* k = (const float*)d_in[1];
  const float* v = (const float*)d_in[2];
  const float* W = (const float*)d_in[3];
  const float* b = (const float*)d_in[4];
  float* out = (float*)d_out;

  float* ws = (float*)d_ws;
  // lifetimes: {qb,kb,lut} dead before part_kv is written (stream order)
  float* part_kv = ws;                              // 16*16*4096 = 1,048,576 f
  float* qb      = ws;                              // alias (dead early)
  float* kb      = ws + 32768;                      // alias (dead early)
  int*   lut     = (int*)(ws + 65536);              // 3072 ints (dead after sparse_attn)
  float* part_ks = ws + 1048576;                    // 16384 f
  float* ksum    = ws + 1064960;                    // 1024 f
  unsigned short* kvwt = (unsigned short*)(ws + 1065984);  // 65536 bf16

  k_blockmean<<<1024, 64, 0, stream>>>(q, k, qb, kb);
  k_topk<<<512, 64, 0, stream>>>(qb, kb, lut);
  k_sparse_attn<<<512, 256, 0, stream>>>(q, k, v, lut, out);
  k_linacc<<<256, 256, 0, stream>>>(k, v, part_kv, part_ks);
  k_fold<<<64, 256, 0, stream>>>(part_kv, part_ks, W, ksum, kvwt);
  k_linout<<<512, 256, 0, stream>>>(q, kvwt, ksum, b, out);
}

// Round 4
// 56.034 us; speedup vs baseline: 4.8527x; 1.1006x over previous
//
#include <hip/hip_runtime.h>
#include <math.h>

#define Hh 16
#define Ll 2048
#define Dd 64
#define MB 32      // L / 64 blocks
#define TK 6

typedef __attribute__((ext_vector_type(8))) short s16x8;
typedef __attribute__((ext_vector_type(4))) short s16x4;
typedef __attribute__((ext_vector_type(4))) float f32x4;

static __device__ __forceinline__ unsigned short f2bf(float x) {
  unsigned int u = __float_as_uint(x);
  return (unsigned short)((u + 0x7fffu + ((u >> 16) & 1u)) >> 16);
}
// byte offset into a [64][64] bf16 tile with 128B rows, XOR-swizzled (T2)
static __device__ __forceinline__ int swz(int row, int bcol) {
  return row * 128 + (bcol ^ ((row & 7) << 4));
}

// ---------------- K1: convert q(scaled)/k to bf16, v to bf16-transposed, + block means ----------------
__global__ __launch_bounds__(256)
void k_prep(const float* __restrict__ q, const float* __restrict__ k,
            const float* __restrict__ v,
            unsigned short* __restrict__ qbf, unsigned short* __restrict__ kbf,
            unsigned short* __restrict__ vt,
            float* __restrict__ qb, float* __restrict__ kb) {
  __shared__ float tile[64][65];
  int bid = blockIdx.x;
  int type = bid >> 9;                       // 0=q, 1=k, 2=v
  int hm = bid & 511;
  int h = hm >> 5, m = hm & 31;
  int t = threadIdx.x;
  const float* src = (type == 0) ? q : (type == 1) ? k : v;
  const float* base = src + (size_t)hm * (64 * Dd);
  int r = t >> 2, c0 = (t & 3) * 16;
  float4 f[4];
#pragma unroll
  for (int i = 0; i < 4; ++i) {
    f[i] = *(const float4*)(base + r * Dd + c0 + i * 4);
    *(float4*)&tile[r][c0 + i * 4] = f[i];
  }
  if (type < 2) {
    float sc = (type == 0) ? 0.125f : 1.0f;
    unsigned short* dst = ((type == 0) ? qbf : kbf) + (size_t)hm * (64 * Dd);
    const float* ff = (const float*)f;
#pragma unroll
    for (int halfi = 0; halfi < 2; ++halfi) {
      s16x8 o;
#pragma unroll
      for (int j = 0; j < 8; ++j) o[j] = f2bf(ff[halfi * 8 + j] * sc);
      *(s16x8*)(dst + r * Dd + c0 + halfi * 8) = o;
    }
    __syncthreads();
    if (t < 64) {
      float s = 0.f;
#pragma unroll 8
      for (int rr = 0; rr < 64; ++rr) s += tile[rr][t];
      ((type == 0) ? qb : kb)[hm * 64 + t] = s * (1.0f / 64.0f);
    }
  } else {
    __syncthreads();
    int d = t >> 2, kc = (t & 3) * 16;
    unsigned short* dst = vt + (size_t)h * Dd * Ll + (size_t)d * Ll + m * 64 + kc;
#pragma unroll
    for (int halfi = 0; halfi < 2; ++halfi) {
      s16x8 o;
#pragma unroll
      for (int j = 0; j < 8; ++j) o[j] = f2bf(tile[kc + halfi * 8 + j][d]);
      *(s16x8*)(dst + halfi * 8) = o;
    }
  }
}

// ---------------- K2: block scores + top-6 ----------------
__global__ void k_topk(const float* __restrict__ qb, const float* __restrict__ kb,
                       int* __restrict__ lut) {
  int hm = blockIdx.x;
  int h = hm / MB;
  __shared__ float sc[MB];
  int n = threadIdx.x;
  if (n < MB) {
    const float* qv = qb + hm * Dd;
    const float* kv = kb + (h * MB + n) * Dd;
    float s = 0.f;
#pragma unroll 8
    for (int d = 0; d < Dd; ++d) s += qv[d] * kv[d];
    sc[n] = s;
  }
  __syncthreads();
  if (threadIdx.x == 0) {
    for (int t = 0; t < TK; ++t) {
      int best = 0; float bv = sc[0];
      for (int n2 = 1; n2 < MB; ++n2) {
        if (sc[n2] > bv) { bv = sc[n2]; best = n2; }
      }
      lut[hm * TK + t] = best;
      sc[best] = -INFINITY;
    }
  }
}

// ---------------- K3: block-sparse flash attention, bf16 MFMA, async staging ----------------
__global__ __launch_bounds__(256, 2)
void k_sparse_attn(const unsigned short* __restrict__ qbf,
                   const unsigned short* __restrict__ kbf,
                   const unsigned short* __restrict__ vt,
                   const int* __restrict__ lut,
                   float* __restrict__ out) {
  __shared__ unsigned short k_s[2][4096];  // [key][d] bf16, swizzled content
  __shared__ unsigned short v_s[2][4096];  // [d][key] bf16 (V^T), swizzled content
  __shared__ unsigned short p_s[4][1024];  // per-wave [16 q][64 key] bf16, swizzled

  int bid = blockIdx.x;
  int hm = (bid & 7) * 64 + (bid >> 3);    // XCD-bijective swizzle
  int h = hm >> 5, m = hm & 31;
  int t = threadIdx.x, w = t >> 6, l = t & 63;
  int g = l >> 4, c16 = l & 15;

  int nbs[TK];
#pragma unroll
  for (int i = 0; i < TK; ++i) nbs[i] = lut[hm * TK + i];

  const unsigned short* qg = qbf + ((size_t)h * Ll + m * 64) * Dd;
  s16x8 aq[2];
#pragma unroll
  for (int kc = 0; kc < 2; ++kc)
    aq[kc] = *(const s16x8*)(qg + (w * 16 + c16) * Dd + kc * 32 + g * 8);

  const unsigned short* kh = kbf + (size_t)h * Ll * Dd;
  const unsigned short* vh = vt + (size_t)h * Dd * Ll;

  // linear LDS dest (uniform + lane*16), pre-swizzled global source (G21)
  auto stage = [&](int buf, int nb) {
    const unsigned short* kb = kh + nb * 64 * Dd;
    const unsigned short* vb = vh + nb * 64;
#pragma unroll
    for (int i = 0; i < 2; ++i) {
      int c = i * 256 + t;
      int row = c >> 3, sub = c & 7;
      int scol = (sub ^ (row & 7)) * 8;
      __builtin_amdgcn_global_load_lds(
          (const __attribute__((address_space(1))) void*)(kb + row * Dd + scol),
          (__attribute__((address_space(3))) void*)&k_s[buf][c * 8], 16, 0, 0);
    }
#pragma unroll
    for (int i = 0; i < 2; ++i) {
      int c = i * 256 + t;
      int row = c >> 3, sub = c & 7;     // row = d index of V^T tile
      int scol = (sub ^ (row & 7)) * 8;
      __builtin_amdgcn_global_load_lds(
          (const __attribute__((address_space(1))) void*)(vb + (size_t)row * Ll + scol),
          (__attribute__((address_space(3))) void*)&v_s[buf][c * 8], 16, 0, 0);
    }
  };

  float mrow[4] = {-INFINITY, -INFINITY, -INFINITY, -INFINITY};
  float lrow[4] = {0.f, 0.f, 0.f, 0.f};
  f32x4 o[4] = {};

  stage(0, nbs[0]);
  __syncthreads();

  for (int kbi = 0; kbi < TK; ++kbi) {
    int buf = kbi & 1;
    if (kbi + 1 < TK) stage(buf ^ 1, nbs[kbi + 1]);

    f32x4 s[4];
#pragma unroll
    for (int nt = 0; nt < 4; ++nt) {
      s16x8 b0 = *(const s16x8*)&k_s[buf][swz(nt * 16 + c16, g * 16) >> 1];
      s16x8 b1 = *(const s16x8*)&k_s[buf][swz(nt * 16 + c16, 64 + g * 16) >> 1];
      f32x4 z = {0.f, 0.f, 0.f, 0.f};
      z = __builtin_amdgcn_mfma_f32_16x16x32_bf16(aq[0], b0, z, 0, 0, 0);
      s[nt] = __builtin_amdgcn_mfma_f32_16x16x32_bf16(aq[1], b1, z, 0, 0, 0);
    }

#pragma unroll
    for (int r = 0; r < 4; ++r) {
      float mx = fmaxf(fmaxf(s[0][r], s[1][r]), fmaxf(s[2][r], s[3][r]));
#pragma unroll
      for (int off = 8; off; off >>= 1) mx = fmaxf(mx, __shfl_xor(mx, off));
      float nm = fmaxf(mrow[r], mx);
      float rs = __expf(mrow[r] - nm);
      float sum = 0.f;
      int qrow = g * 4 + r;
#pragma unroll
      for (int nt = 0; nt < 4; ++nt) {
        float pv = __expf(s[nt][r] - nm);
        sum += pv;
        p_s[w][swz(qrow, (nt * 16 + c16) * 2) >> 1] = f2bf(pv);
      }
#pragma unroll
      for (int off = 8; off; off >>= 1) sum += __shfl_xor(sum, off);
      lrow[r] = lrow[r] * rs + sum;
      mrow[r] = nm;
      o[0][r] *= rs; o[1][r] *= rs; o[2][r] *= rs; o[3][r] *= rs;
    }

    // wave-private p_s RAW: drain LDS writes before fragment reads
    asm volatile("s_waitcnt lgkmcnt(0)" ::: "memory");
    __builtin_amdgcn_sched_barrier(0);

    s16x8 ap0 = *(const s16x8*)&p_s[w][swz(c16, g * 16) >> 1];
    s16x8 ap1 = *(const s16x8*)&p_s[w][swz(c16, 64 + g * 16) >> 1];
#pragma unroll
    for (int nt = 0; nt < 4; ++nt) {
      s16x8 b0 = *(const s16x8*)&v_s[buf][swz(nt * 16 + c16, g * 16) >> 1];
      s16x8 b1 = *(const s16x8*)&v_s[buf][swz(nt * 16 + c16, 64 + g * 16) >> 1];
      o[nt] = __builtin_amdgcn_mfma_f32_16x16x32_bf16(ap0, b0, o[nt], 0, 0, 0);
      o[nt] = __builtin_amdgcn_mfma_f32_16x16x32_bf16(ap1, b1, o[nt], 0, 0, 0);
    }
    __syncthreads();   // drains vmcnt(0) too: next-tile global_load_lds complete
  }

  float* ob = out + ((size_t)h * Ll + m * 64 + w * 16) * Dd;
#pragma unroll
  for (int r = 0; r < 4; ++r) {
    float inv = 1.0f / lrow[r];
    int qrow = g * 4 + r;
#pragma unroll
    for (int nt = 0; nt < 4; ++nt)
      ob[qrow * Dd + nt * 16 + c16] = o[nt][r] * inv;
  }
}

// ---------------- K4: kv/ksum partials, no atomics ----------------
__global__ __launch_bounds__(256)
void k_linacc(const float* __restrict__ k, const float* __restrict__ v,
              float* __restrict__ part_kv, float* __restrict__ part_ks) {
  __shared__ float kf_s[64][68];
  __shared__ float v_sh[64][68];
  int h = blockIdx.x >> 4, c = blockIdx.x & 15;   // 16 chunks of 128 rows
  int t = threadIdx.x;
  int rg = t >> 4;
  int c4 = (t & 15) * 4;
  int da0 = (t >> 4) * 4, e0 = (t & 15) * 4;
  float kvacc[4][4] = {};
  float ks4[4] = {0.f, 0.f, 0.f, 0.f};
  const size_t hbase = (size_t)h * Ll * Dd;
  int rbase = c * 128;

  for (int half = 0; half < 2; ++half) {
#pragma unroll
    for (int ch = 0; ch < 4; ++ch) {
      int rl = ch * 16 + rg;
      int row = rbase + half * 64 + rl;
      float4 kq = *(const float4*)(k + hbase + (size_t)row * Dd + c4);
      float4 vv = *(const float4*)(v + hbase + (size_t)row * Dd + c4);
      float mx = fmaxf(fmaxf(kq.x, kq.y), fmaxf(kq.z, kq.w));
#pragma unroll
      for (int off = 8; off; off >>= 1) mx = fmaxf(mx, __shfl_xor(mx, off));
      float ex = __expf(kq.x - mx), ey = __expf(kq.y - mx);
      float ez = __expf(kq.z - mx), ew = __expf(kq.w - mx);
      float sm = ex + ey + ez + ew;
#pragma unroll
      for (int off = 8; off; off >>= 1) sm += __shfl_xor(sm, off);
      float inv = 1.0f / sm;
      *(float4*)&kf_s[rl][c4] = make_float4(ex * inv, ey * inv, ez * inv, ew * inv);
      *(float4*)&v_sh[rl][c4] = vv;
    }
    __syncthreads();
    for (int r = 0; r < 64; ++r) {
      float4 kf = *(const float4*)&kf_s[r][da0];
      float4 vv = *(const float4*)&v_sh[r][e0];
      ks4[0] += kf.x; ks4[1] += kf.y; ks4[2] += kf.z; ks4[3] += kf.w;
      kvacc[0][0] += kf.x * vv.x; kvacc[0][1] += kf.x * vv.y; kvacc[0][2] += kf.x * vv.z; kvacc[0][3] += kf.x * vv.w;
      kvacc[1][0] += kf.y * vv.x; kvacc[1][1] += kf.y * vv.y; kvacc[1][2] += kf.y * vv.z; kvacc[1][3] += kf.y * vv.w;
      kvacc[2][0] += kf.z * vv.x; kvacc[2][1] += kf.z * vv.y; kvacc[2][2] += kf.z * vv.z; kvacc[2][3] += kf.z * vv.w;
      kvacc[3][0] += kf.w * vv.x; kvacc[3][1] += kf.w * vv.y; kvacc[3][2] += kf.w * vv.z; kvacc[3][3] += kf.w * vv.w;
    }
    __syncthreads();
  }
  float* pkv = part_kv + (size_t)blockIdx.x * 4096;
#pragma unroll
  for (int i = 0; i < 4; ++i)
    *(float4*)(pkv + (da0 + i) * 64 + e0) =
        make_float4(kvacc[i][0], kvacc[i][1], kvacc[i][2], kvacc[i][3]);
  if ((t & 15) == 0) {
#pragma unroll
    for (int i = 0; i < 4; ++i) part_ks[blockIdx.x * 64 + da0 + i] = ks4[i];
  }
}

// ---------------- K5: reduce partials + fold W -> kvWt bf16 ----------------
__global__ __launch_bounds__(256)
void k_fold(const float* __restrict__ part_kv, const float* __restrict__ part_ks,
            const float* __restrict__ W, float* __restrict__ ksum,
            unsigned short* __restrict__ kvwt) {
  __shared__ float kvr[16][68];
  __shared__ float w_s[64][65];
  int h = blockIdx.x >> 2, qtr = blockIdx.x & 3;
  int a0 = qtr * 16;
  int t = threadIdx.x;
  {
    int a = t >> 4, b4 = (t & 15) * 4;
    float4 acc = make_float4(0.f, 0.f, 0.f, 0.f);
    for (int cc = 0; cc < 16; ++cc) {
      float4 p = *(const float4*)(part_kv + (size_t)(h * 16 + cc) * 4096 + (a0 + a) * 64 + b4);
      acc.x += p.x; acc.y += p.y; acc.z += p.z; acc.w += p.w;
    }
    *(float4*)&kvr[a][b4] = acc;
    int r = t >> 2, cq = (t & 3) * 16;
#pragma unroll
    for (int j = 0; j < 16; ++j) w_s[r][cq + j] = W[r * 64 + cq + j];
    if (qtr == 0 && t < 64) {
      float s = 0.f;
      for (int cc = 0; cc < 16; ++cc) s += part_ks[(h * 16 + cc) * 64 + t];
      ksum[h * 64 + t] = s;
    }
  }
  __syncthreads();
  int e = t & 63, ag = t >> 6;
  float acc4[4] = {0.f, 0.f, 0.f, 0.f};
  for (int b = 0; b < 64; ++b) {
    float wv = w_s[e][b];
#pragma unroll
    for (int i = 0; i < 4; ++i) acc4[i] += kvr[ag * 4 + i][b] * wv;
  }
#pragma unroll
  for (int i = 0; i < 4; ++i)
    kvwt[h * 4096 + e * 64 + a0 + ag * 4 + i] = f2bf(acc4[i]);
}

// ---------------- K6: o_l via MFMA, added to out ----------------
__global__ __launch_bounds__(256)
void k_linout(const float* __restrict__ q, const unsigned short* __restrict__ kvwt,
              const float* __restrict__ ksum, const float* __restrict__ bproj,
              float* __restrict__ out) {
  __shared__ unsigned short kvwt_s[4096];   // [e][a] bf16 swizzled
  __shared__ unsigned short qf_s[4][1024];  // per-wave [16 q][64 a] bf16 swizzled
  __shared__ float ks_s[64], b_s[64];
  __shared__ float den_s[4][16];
  int h = blockIdx.x >> 5, c = blockIdx.x & 31;
  int t = threadIdx.x, w = t >> 6, l = t & 63;
  int g = l >> 4, c16 = l & 15;
  int c4 = c16 * 4;

#pragma unroll
  for (int cc = 0; cc < 2; ++cc) {
    int idx = t + cc * 256;
    int row = idx >> 3, col8 = idx & 7;
    s16x8 val = *(const s16x8*)(kvwt + h * 4096 + row * 64 + col8 * 8);
    *(s16x8*)&kvwt_s[swz(row, col8 * 16) >> 1] = val;
  }
  if (t < 64) { ks_s[t] = ksum[h * 64 + t]; b_s[t] = bproj[t]; }
  __syncthreads();

  const float* qg = q + ((size_t)h * Ll + c * 64 + w * 16) * Dd;
#pragma unroll
  for (int p = 0; p < 4; ++p) {
    int rl = p * 4 + g;
    float4 qv = *(const float4*)(qg + rl * Dd + c4);
    float mx = fmaxf(fmaxf(qv.x, qv.y), fmaxf(qv.z, qv.w));
#pragma unroll
    for (int off = 8; off; off >>= 1) mx = fmaxf(mx, __shfl_xor(mx, off));
    float ex = __expf(qv.x - mx), ey = __expf(qv.y - mx);
    float ez = __expf(qv.z - mx), ew = __expf(qv.w - mx);
    float sm = ex + ey + ez + ew;
#pragma unroll
    for (int off = 8; off; off >>= 1) sm += __shfl_xor(sm, off);
    float inv = 1.0f / sm;
    float fx = ex * inv, fy = ey * inv, fz = ez * inv, fw = ew * inv;
    float dp = fx * ks_s[c4] + fy * ks_s[c4 + 1] + fz * ks_s[c4 + 2] + fw * ks_s[c4 + 3];
#pragma unroll
    for (int off = 8; off; off >>= 1) dp += __shfl_xor(dp, off);
    if (c16 == 0) den_s[w][rl] = dp + 1e-5f;
    s16x4 pk;
    pk[0] = f2bf(fx); pk[1] = f2bf(fy); pk[2] = f2bf(fz); pk[3] = f2bf(fw);
    *(s16x4*)&qf_s[w][swz(rl, c4 * 2) >> 1] = pk;
  }
  asm volatile("s_waitcnt lgkmcnt(0)" ::: "memory");
  __builtin_amdgcn_sched_barrier(0);

  s16x8 ap0 = *(const s16x8*)&qf_s[w][swz(c16, g * 16) >> 1];
  s16x8 ap1 = *(const s16x8*)&qf_s[w][swz(c16, 64 + g * 16) >> 1];
  f32x4 o[4];
#pragma unroll
  for (int nt = 0; nt < 4; ++nt) {
    s16x8 b0 = *(const s16x8*)&kvwt_s[swz(nt * 16 + c16, g * 16) >> 1];
    s16x8 b1 = *(const s16x8*)&kvwt_s[swz(nt * 16 + c16, 64 + g * 16) >> 1];
    f32x4 z = {0.f, 0.f, 0.f, 0.f};
    z = __builtin_amdgcn_mfma_f32_16x16x32_bf16(ap0, b0, z, 0, 0, 0);
    o[nt] = __builtin_amdgcn_mfma_f32_16x16x32_bf16(ap1, b1, z, 0, 0, 0);
  }

  float* ob = out + ((size_t)h * Ll + c * 64 + w * 16) * Dd;
#pragma unroll
  for (int r = 0; r < 4; ++r) {
    int qrow = g * 4 + r;
    float invd = 1.0f / den_s[w][qrow];
#pragma unroll
    for (int nt = 0; nt < 4; ++nt)
      ob[qrow * Dd + nt * 16 + c16] += o[nt][r] * invd + b_s[nt * 16 + c16];
  }
}

extern "C" void kernel_launch(void* const* d_in, const int* in_sizes, int n_in,
                              void* d_out, int out_size, void* d_ws, size_t ws_size,
                              hipStream_t stream) {
  const float* q = (const float*)d_in[0];
  const float* k = (const float*)d_in[1];
  const float* v = (const float*)d_in[2];
  const float* W = (const float*)d_in[3];
  const float* b = (const float*)d_in[4];
  float* out = (float*)d_out;

  char* wsb = (char*)d_ws;                                  // ws_size ~256MB; we use ~17.3MB
  unsigned short* qbf = (unsigned short*)(wsb);             // 4 MB  (bf16, prescaled 0.125)
  unsigned short* kbf = (unsigned short*)(wsb + 4194304);   // 4 MB
  unsigned short* vt  = (unsigned short*)(wsb + 8388608);   // 4 MB  (V^T: [h][d][key])
  float* qb      = (float*)(wsb + 12582912);                // 128 KB
  float* kb      = (float*)(wsb + 12713984);                // 128 KB
  int*   lut     = (int*)(wsb + 12845056);                  // 12 KB
  float* part_kv = (float*)(wsb + 12857344);                // 4 MB
  float* part_ks = (float*)(wsb + 17051648);                // 64 KB
  float* ksum    = (float*)(wsb + 17117184);                // 4 KB
  unsigned short* kvwt = (unsigned short*)(wsb + 17121280); // 128 KB

  k_prep<<<1536, 256, 0, stream>>>(q, k, v, qbf, kbf, vt, qb, kb);
  k_topk<<<512, 64, 0, stream>>>(qb, kb, lut);
  k_sparse_attn<<<512, 256, 0, stream>>>(qbf, kbf, vt, lut, out);
  k_linacc<<<256, 256, 0, stream>>>(k, v, part_kv, part_ks);
  k_fold<<<64, 256, 0, stream>>>(part_kv, part_ks, W, ksum, kvwt);
  k_linout<<<512, 256, 0, stream>>>(q, kvwt, ksum, b, out);
}

// Round 5
// 42.504 us; speedup vs baseline: 6.3975x; 1.3183x over previous
//
#include <hip/hip_runtime.h>
#include <math.h>

#define Hh 16
#define Ll 2048
#define Dd 64
#define MB 32      // L / 64 blocks
#define TK 6

typedef __attribute__((ext_vector_type(8))) short s16x8;
typedef __attribute__((ext_vector_type(4))) float f32x4;

static __device__ __forceinline__ unsigned short f2bf(float x) {
  unsigned int u = __float_as_uint(x);
  return (unsigned short)((u + 0x7fffu + ((u >> 16) & 1u)) >> 16);
}
static __device__ __forceinline__ float bf2f(short b) {
  return __uint_as_float(((unsigned int)(unsigned short)b) << 16);
}
// byte offset into a [64][64] bf16 tile with 128B rows, XOR-swizzled (T2)
static __device__ __forceinline__ int swz(int row, int bcol) {
  return row * 128 + (bcol ^ ((row & 7) << 4));
}

// ---------------- K1: prep (bf16 convert + V^T + block means) fused with linacc ----------------
__global__ __launch_bounds__(256)
void k_prep(const float* __restrict__ q, const float* __restrict__ k,
            const float* __restrict__ v,
            unsigned short* __restrict__ qbf, unsigned short* __restrict__ kbf,
            unsigned short* __restrict__ vt,
            float* __restrict__ qb, float* __restrict__ kb,
            float* __restrict__ part_kv, float* __restrict__ part_ks) {
  __shared__ float tile[64][65];   // q then k (reused)
  __shared__ float kf_s[64][68];
  __shared__ float v_sh[64][68];
  int hm = blockIdx.x;             // (h,m)
  int h = hm >> 5, m = hm & 31;
  int t = threadIdx.x;
  int r = t >> 2, c0 = (t & 3) * 16;
  const size_t base = (size_t)hm * (64 * Dd);

  // ---- phase A: q -> tile + qbf ; v -> v_sh ----
  {
    float4 f[4];
#pragma unroll
    for (int i = 0; i < 4; ++i) {
      f[i] = *(const float4*)(q + base + r * Dd + c0 + i * 4);
      *(float4*)&tile[r][c0 + i * 4] = f[i];
      float4 vv = *(const float4*)(v + base + r * Dd + c0 + i * 4);
      *(float4*)&v_sh[r][c0 + i * 4] = vv;
    }
    const float* ff = (const float*)f;
    unsigned short* dst = qbf + base;
#pragma unroll
    for (int halfi = 0; halfi < 2; ++halfi) {
      s16x8 o;
#pragma unroll
      for (int j = 0; j < 8; ++j) o[j] = (short)f2bf(ff[halfi * 8 + j] * 0.125f);
      *(s16x8*)(dst + r * Dd + c0 + halfi * 8) = o;
    }
  }
  __syncthreads();
  // q column means
  if (t < 64) {
    float s = 0.f;
#pragma unroll 8
    for (int rr = 0; rr < 64; ++rr) s += tile[rr][t];
    qb[hm * 64 + t] = s * (1.0f / 64.0f);
  }
  // V^T bf16 out (reads v_sh)
  {
    int d = t >> 2, kc = (t & 3) * 16;
    unsigned short* dst = vt + (size_t)h * Dd * Ll + (size_t)d * Ll + m * 64 + kc;
#pragma unroll
    for (int halfi = 0; halfi < 2; ++halfi) {
      s16x8 o;
#pragma unroll
      for (int j = 0; j < 8; ++j) o[j] = (short)f2bf(v_sh[kc + halfi * 8 + j][d]);
      *(s16x8*)(dst + halfi * 8) = o;
    }
  }
  __syncthreads();   // protect tile before k overwrite

  // ---- phase B: k -> tile + kbf ----
  {
    float4 f[4];
#pragma unroll
    for (int i = 0; i < 4; ++i) {
      f[i] = *(const float4*)(k + base + r * Dd + c0 + i * 4);
      *(float4*)&tile[r][c0 + i * 4] = f[i];
    }
    const float* ff = (const float*)f;
    unsigned short* dst = kbf + base;
#pragma unroll
    for (int halfi = 0; halfi < 2; ++halfi) {
      s16x8 o;
#pragma unroll
      for (int j = 0; j < 8; ++j) o[j] = (short)f2bf(ff[halfi * 8 + j]);
      *(s16x8*)(dst + r * Dd + c0 + halfi * 8) = o;
    }
  }
  __syncthreads();
  // k column means
  if (t < 64) {
    float s = 0.f;
#pragma unroll 8
    for (int rr = 0; rr < 64; ++rr) s += tile[rr][t];
    kb[hm * 64 + t] = s * (1.0f / 64.0f);
  }
  // k_feat row softmax -> kf_s
  {
    int rg = t >> 4;                 // 16 groups of 16 lanes
    int c4 = (t & 15) * 4;
#pragma unroll
    for (int ch = 0; ch < 4; ++ch) {
      int rl = ch * 16 + rg;
      float4 kq = *(const float4*)&tile[rl][c4];
      float mx = fmaxf(fmaxf(kq.x, kq.y), fmaxf(kq.z, kq.w));
#pragma unroll
      for (int off = 8; off; off >>= 1) mx = fmaxf(mx, __shfl_xor(mx, off));
      float ex = __expf(kq.x - mx), ey = __expf(kq.y - mx);
      float ez = __expf(kq.z - mx), ew = __expf(kq.w - mx);
      float sm = ex + ey + ez + ew;
#pragma unroll
      for (int off = 8; off; off >>= 1) sm += __shfl_xor(sm, off);
      float inv = 1.0f / sm;
      *(float4*)&kf_s[rl][c4] = make_float4(ex * inv, ey * inv, ez * inv, ew * inv);
    }
  }
  __syncthreads();
  // partial kv outer product + ks
  {
    int da0 = (t >> 4) * 4, e0 = (t & 15) * 4;
    float kvacc[4][4] = {};
    float ks4[4] = {0.f, 0.f, 0.f, 0.f};
    for (int rr = 0; rr < 64; ++rr) {
      float4 kf = *(const float4*)&kf_s[rr][da0];
      float4 vv = *(const float4*)&v_sh[rr][e0];
      ks4[0] += kf.x; ks4[1] += kf.y; ks4[2] += kf.z; ks4[3] += kf.w;
      kvacc[0][0] += kf.x * vv.x; kvacc[0][1] += kf.x * vv.y; kvacc[0][2] += kf.x * vv.z; kvacc[0][3] += kf.x * vv.w;
      kvacc[1][0] += kf.y * vv.x; kvacc[1][1] += kf.y * vv.y; kvacc[1][2] += kf.y * vv.z; kvacc[1][3] += kf.y * vv.w;
      kvacc[2][0] += kf.z * vv.x; kvacc[2][1] += kf.z * vv.y; kvacc[2][2] += kf.z * vv.z; kvacc[2][3] += kf.z * vv.w;
      kvacc[3][0] += kf.w * vv.x; kvacc[3][1] += kf.w * vv.y; kvacc[3][2] += kf.w * vv.z; kvacc[3][3] += kf.w * vv.w;
    }
    float* pkv = part_kv + (size_t)hm * 4096;
#pragma unroll
    for (int i = 0; i < 4; ++i)
      *(float4*)(pkv + (da0 + i) * 64 + e0) =
          make_float4(kvacc[i][0], kvacc[i][1], kvacc[i][2], kvacc[i][3]);
    if ((t & 15) == 0) {
#pragma unroll
      for (int i = 0; i < 4; ++i) part_ks[hm * 64 + da0 + i] = ks4[i];
    }
  }
}

// ---------------- K2: topk (wave-parallel) + fold, fused launch ----------------
__global__ __launch_bounds__(256)
void k_topk_fold(const float* __restrict__ qb, const float* __restrict__ kb,
                 int* __restrict__ lut,
                 const float* __restrict__ part_kv, const float* __restrict__ part_ks,
                 const float* __restrict__ W, float* __restrict__ ksum,
                 unsigned short* __restrict__ kvwt) {
  __shared__ float kvr[16][68];
  __shared__ float w_s[64][65];
  int blk = blockIdx.x;
  int t = threadIdx.x;
  if (blk < 128) {
    // ---- topk: one wave per q-block ----
    int w = t >> 6, l = t & 63;
    int hm = blk * 4 + w;
    int hh = hm >> 5;
    float val = -INFINITY;
    if (l < 32) {
      const float* qv = qb + hm * 64;
      const float* kv = kb + (hh * 32 + l) * 64;
      float s = 0.f;
#pragma unroll 8
      for (int d = 0; d < 64; ++d) s += qv[d] * kv[d];
      val = s;
    }
    int idx = l & 31;
    for (int t6 = 0; t6 < TK; ++t6) {
      float bv = val; int bi = idx;
#pragma unroll
      for (int off = 32; off; off >>= 1) {
        float ov = __shfl_xor(bv, off);
        int oi = __shfl_xor(bi, off);
        if (ov > bv || (ov == bv && oi < bi)) { bv = ov; bi = oi; }
      }
      if (l == 0) lut[hm * TK + t6] = bi;
      if (idx == bi && l < 32) val = -INFINITY;
    }
  } else {
    // ---- fold: reduce 32 partials + kvW^T bf16 ----
    int fidx = blk - 128;
    int h = fidx >> 2, qtr = fidx & 3;
    int a0 = qtr * 16;
    {
      int a = t >> 4, b4 = (t & 15) * 4;
      float4 acc = make_float4(0.f, 0.f, 0.f, 0.f);
      for (int cc = 0; cc < 32; ++cc) {
        float4 p = *(const float4*)(part_kv + (size_t)(h * 32 + cc) * 4096 + (a0 + a) * 64 + b4);
        acc.x += p.x; acc.y += p.y; acc.z += p.z; acc.w += p.w;
      }
      *(float4*)&kvr[a][b4] = acc;
      int r = t >> 2, cq = (t & 3) * 16;
#pragma unroll
      for (int j = 0; j < 16; ++j) w_s[r][cq + j] = W[r * 64 + cq + j];
      if (qtr == 0 && t < 64) {
        float s = 0.f;
        for (int cc = 0; cc < 32; ++cc) s += part_ks[(h * 32 + cc) * 64 + t];
        ksum[h * 64 + t] = s;
      }
    }
    __syncthreads();
    int e = t & 63, ag = t >> 6;
    float acc4[4] = {0.f, 0.f, 0.f, 0.f};
    for (int b = 0; b < 64; ++b) {
      float wv = w_s[e][b];
#pragma unroll
      for (int i = 0; i < 4; ++i) acc4[i] += kvr[ag * 4 + i][b] * wv;
    }
#pragma unroll
    for (int i = 0; i < 4; ++i)
      kvwt[h * 4096 + e * 64 + a0 + ag * 4 + i] = f2bf(acc4[i]);
  }
}

// ---------------- K3: block-sparse flash attention + fused linear epilogue ----------------
__global__ __launch_bounds__(256, 2)
void k_attn(const unsigned short* __restrict__ qbf,
            const unsigned short* __restrict__ kbf,
            const unsigned short* __restrict__ vt,
            const int* __restrict__ lut,
            const unsigned short* __restrict__ kvwt,
            const float* __restrict__ ksum, const float* __restrict__ bproj,
            float* __restrict__ out) {
  __shared__ unsigned short k_s[2][4096];  // [key][d] bf16, swizzled content
  __shared__ unsigned short v_s[2][4096];  // [d][key] bf16 (V^T), swizzled content
  __shared__ unsigned short p_s[4][1024];  // per-wave [16 q][64 key] bf16, swizzled
  __shared__ unsigned short kvwt_s[4096];  // [e][a] bf16 swizzled
  __shared__ float ks_s[64], b_s[64];
  __shared__ float den_s[4][16];

  int bid = blockIdx.x;
  int hm = (bid & 7) * 64 + (bid >> 3);    // XCD-bijective swizzle
  int h = hm >> 5, m = hm & 31;
  int t = threadIdx.x, w = t >> 6, l = t & 63;
  int g = l >> 4, c16 = l & 15;

  int nbs[TK];
#pragma unroll
  for (int i = 0; i < TK; ++i) nbs[i] = lut[hm * TK + i];

  const unsigned short* qg = qbf + ((size_t)h * Ll + m * 64) * Dd;
  s16x8 aq[2];
#pragma unroll
  for (int kc = 0; kc < 2; ++kc)
    aq[kc] = *(const s16x8*)(qg + (w * 16 + c16) * Dd + kc * 32 + g * 8);

  // stage kvwt/ksum/bias for the linear epilogue
#pragma unroll
  for (int cc = 0; cc < 2; ++cc) {
    int idx = t + cc * 256;
    int row = idx >> 3, col8 = idx & 7;
    s16x8 val = *(const s16x8*)(kvwt + h * 4096 + row * 64 + col8 * 8);
    *(s16x8*)&kvwt_s[swz(row, col8 * 16) >> 1] = val;
  }
  if (t < 64) { ks_s[t] = ksum[h * 64 + t]; b_s[t] = bproj[t]; }

  const unsigned short* kh = kbf + (size_t)h * Ll * Dd;
  const unsigned short* vh = vt + (size_t)h * Dd * Ll;

  // linear LDS dest, pre-swizzled global source (G21)
  auto stage = [&](int buf, int nb) {
    const unsigned short* kb = kh + nb * 64 * Dd;
    const unsigned short* vb = vh + nb * 64;
#pragma unroll
    for (int i = 0; i < 2; ++i) {
      int c = i * 256 + t;
      int row = c >> 3, sub = c & 7;
      int scol = (sub ^ (row & 7)) * 8;
      __builtin_amdgcn_global_load_lds(
          (const __attribute__((address_space(1))) void*)(kb + row * Dd + scol),
          (__attribute__((address_space(3))) void*)&k_s[buf][c * 8], 16, 0, 0);
    }
#pragma unroll
    for (int i = 0; i < 2; ++i) {
      int c = i * 256 + t;
      int row = c >> 3, sub = c & 7;
      int scol = (sub ^ (row & 7)) * 8;
      __builtin_amdgcn_global_load_lds(
          (const __attribute__((address_space(1))) void*)(vb + (size_t)row * Ll + scol),
          (__attribute__((address_space(3))) void*)&v_s[buf][c * 8], 16, 0, 0);
    }
  };

  float mrow[4] = {-INFINITY, -INFINITY, -INFINITY, -INFINITY};
  float lrow[4] = {0.f, 0.f, 0.f, 0.f};
  f32x4 o[4] = {};

  stage(0, nbs[0]);
  __syncthreads();

  for (int kbi = 0; kbi < TK; ++kbi) {
    int buf = kbi & 1;
    if (kbi + 1 < TK) stage(buf ^ 1, nbs[kbi + 1]);

    f32x4 s[4];
#pragma unroll
    for (int nt = 0; nt < 4; ++nt) {
      s16x8 b0 = *(const s16x8*)&k_s[buf][swz(nt * 16 + c16, g * 16) >> 1];
      s16x8 b1 = *(const s16x8*)&k_s[buf][swz(nt * 16 + c16, 64 + g * 16) >> 1];
      f32x4 z = {0.f, 0.f, 0.f, 0.f};
      z = __builtin_amdgcn_mfma_f32_16x16x32_bf16(aq[0], b0, z, 0, 0, 0);
      s[nt] = __builtin_amdgcn_mfma_f32_16x16x32_bf16(aq[1], b1, z, 0, 0, 0);
    }

#pragma unroll
    for (int r = 0; r < 4; ++r) {
      float mx = fmaxf(fmaxf(s[0][r], s[1][r]), fmaxf(s[2][r], s[3][r]));
#pragma unroll
      for (int off = 8; off; off >>= 1) mx = fmaxf(mx, __shfl_xor(mx, off));
      float nm = fmaxf(mrow[r], mx);
      float rs = __expf(mrow[r] - nm);
      float sum = 0.f;
      int qrow = g * 4 + r;
#pragma unroll
      for (int nt = 0; nt < 4; ++nt) {
        float pv = __expf(s[nt][r] - nm);
        sum += pv;
        p_s[w][swz(qrow, (nt * 16 + c16) * 2) >> 1] = f2bf(pv);
      }
#pragma unroll
      for (int off = 8; off; off >>= 1) sum += __shfl_xor(sum, off);
      lrow[r] = lrow[r] * rs + sum;
      mrow[r] = nm;
      o[0][r] *= rs; o[1][r] *= rs; o[2][r] *= rs; o[3][r] *= rs;
    }

    // wave-private p_s RAW: drain LDS writes before fragment reads
    asm volatile("s_waitcnt lgkmcnt(0)" ::: "memory");
    __builtin_amdgcn_sched_barrier(0);

    s16x8 ap0 = *(const s16x8*)&p_s[w][swz(c16, g * 16) >> 1];
    s16x8 ap1 = *(const s16x8*)&p_s[w][swz(c16, 64 + g * 16) >> 1];
#pragma unroll
    for (int nt = 0; nt < 4; ++nt) {
      s16x8 b0 = *(const s16x8*)&v_s[buf][swz(nt * 16 + c16, g * 16) >> 1];
      s16x8 b1 = *(const s16x8*)&v_s[buf][swz(nt * 16 + c16, 64 + g * 16) >> 1];
      o[nt] = __builtin_amdgcn_mfma_f32_16x16x32_bf16(ap0, b0, o[nt], 0, 0, 0);
      o[nt] = __builtin_amdgcn_mfma_f32_16x16x32_bf16(ap1, b1, o[nt], 0, 0, 0);
    }
    __syncthreads();   // drains vmcnt(0) too: next-tile global_load_lds complete
  }

  // ---- fused linear-attention epilogue (in-register qf softmax) ----
  float qf0[8], qf1[8];
  float mx = -INFINITY;
#pragma unroll
  for (int j = 0; j < 8; ++j) {
    qf0[j] = bf2f(aq[0][j]) * 8.f;
    qf1[j] = bf2f(aq[1][j]) * 8.f;
    mx = fmaxf(mx, fmaxf(qf0[j], qf1[j]));
  }
  mx = fmaxf(mx, __shfl_xor(mx, 16));
  mx = fmaxf(mx, __shfl_xor(mx, 32));
  float sm = 0.f;
#pragma unroll
  for (int j = 0; j < 8; ++j) {
    qf0[j] = __expf(qf0[j] - mx);
    qf1[j] = __expf(qf1[j] - mx);
    sm += qf0[j] + qf1[j];
  }
  sm += __shfl_xor(sm, 16);
  sm += __shfl_xor(sm, 32);
  float qinv = 1.0f / sm;
  float dp = 0.f;
#pragma unroll
  for (int j = 0; j < 8; ++j) {
    qf0[j] *= qinv; qf1[j] *= qinv;
    dp += qf0[j] * ks_s[g * 8 + j] + qf1[j] * ks_s[32 + g * 8 + j];
  }
  dp += __shfl_xor(dp, 16);
  dp += __shfl_xor(dp, 32);
  if (g == 0) den_s[w][c16] = dp + 1e-5f;
  s16x8 pa0, pa1;
#pragma unroll
  for (int j = 0; j < 8; ++j) {
    pa0[j] = (short)f2bf(qf0[j]);
    pa1[j] = (short)f2bf(qf1[j]);
  }
  asm volatile("s_waitcnt lgkmcnt(0)" ::: "memory");
  __builtin_amdgcn_sched_barrier(0);

  f32x4 ol[4];
#pragma unroll
  for (int nt = 0; nt < 4; ++nt) {
    s16x8 b0 = *(const s16x8*)&kvwt_s[swz(nt * 16 + c16, g * 16) >> 1];
    s16x8 b1 = *(const s16x8*)&kvwt_s[swz(nt * 16 + c16, 64 + g * 16) >> 1];
    f32x4 z = {0.f, 0.f, 0.f, 0.f};
    z = __builtin_amdgcn_mfma_f32_16x16x32_bf16(pa0, b0, z, 0, 0, 0);
    ol[nt] = __builtin_amdgcn_mfma_f32_16x16x32_bf16(pa1, b1, z, 0, 0, 0);
  }

  float* ob = out + ((size_t)h * Ll + m * 64 + w * 16) * Dd;
#pragma unroll
  for (int r = 0; r < 4; ++r) {
    float inv_l = 1.0f / lrow[r];
    int qrow = g * 4 + r;
    float invd = 1.0f / den_s[w][qrow];
#pragma unroll
    for (int nt = 0; nt < 4; ++nt)
      ob[qrow * Dd + nt * 16 + c16] =
          o[nt][r] * inv_l + ol[nt][r] * invd + b_s[nt * 16 + c16];
  }
}

extern "C" void kernel_launch(void* const* d_in, const int* in_sizes, int n_in,
                              void* d_out, int out_size, void* d_ws, size_t ws_size,
                              hipStream_t stream) {
  const float* q = (const float*)d_in[0];
  const float* k = (const float*)d_in[1];
  const float* v = (const float*)d_in[2];
  const float* W = (const float*)d_in[3];
  const float* b = (const float*)d_in[4];
  float* out = (float*)d_out;

  char* wsb = (char*)d_ws;
  unsigned short* qbf = (unsigned short*)(wsb);             // 4 MB
  unsigned short* kbf = (unsigned short*)(wsb + 4194304);   // 4 MB
  unsigned short* vt  = (unsigned short*)(wsb + 8388608);   // 4 MB
  float* qb      = (float*)(wsb + 12582912);                // 128 KB
  float* kb      = (float*)(wsb + 12713984);                // 128 KB
  int*   lut     = (int*)(wsb + 12845056);                  // 12 KB
  float* part_kv = (float*)(wsb + 12857344);                // 8 MB (512 x 4096 f)
  float* part_ks = (float*)(wsb + 21245952);                // 128 KB
  float* ksum    = (float*)(wsb + 21377024);                // 4 KB
  unsigned short* kvwt = (unsigned short*)(wsb + 21381120); // 128 KB

  k_prep<<<512, 256, 0, stream>>>(q, k, v, qbf, kbf, vt, qb, kb, part_kv, part_ks);
  k_topk_fold<<<192, 256, 0, stream>>>(qb, kb, lut, part_kv, part_ks, W, ksum, kvwt);
  k_attn<<<512, 256, 0, stream>>>(qbf, kbf, vt, lut, kvwt, ksum, b, out);
}